// Round 10
// baseline (179.811 us; speedup 1.0000x reference)
//
#include <hip/hip_runtime.h>
#include <math.h>

// Problem constants
constexpr int NB  = 8;     // batch
constexpr int C   = 256;   // channels
constexpr int T   = 1024;  // pixels (32*32)
constexpr int NH  = 8;     // heads
constexpr int HD  = 32;    // head dim
constexpr int C3  = 768;   // 3*C

// Q pre-scale: (1/sqrt(32)) * log2(e)  -> softmax body is a bare v_exp_f32
constexpr float QSCALE = 0.25503489422229562f;

typedef __attribute__((ext_vector_type(8))) short bf16x8;
typedef __attribute__((ext_vector_type(4))) float f32x4;

__device__ inline short f2bf(float f) {            // round-to-nearest-even
    unsigned u = __float_as_uint(f);
    u += 0x7FFF + ((u >> 16) & 1);
    return (short)(u >> 16);
}
__device__ inline short f2bf_trunc(float f) {      // 1-op truncation (P only)
    return (short)(__float_as_uint(f) >> 16);
}

__device__ __forceinline__ f32x4 mfma32(bf16x8 a, bf16x8 b, f32x4 c) {
    return __builtin_amdgcn_mfma_f32_16x16x32_bf16(a, b, c, 0, 0, 0);
}

// async global->LDS, 16B per lane. Dest must be wave-uniform base + lane*16.
__device__ __forceinline__ void gl16(const void* g, void* l) {
    __builtin_amdgcn_global_load_lds(
        (const __attribute__((address_space(1))) unsigned int*)g,
        (__attribute__((address_space(3))) unsigned int*)l, 16, 0, 0);
}

// ---------------------------------------------------------------------------
// Kernel 0: one-time transpose+convert to bf16, k-contiguous layouts.
//   image [nb][256 c][1024 t] f32 -> Xb  [nb][1024 t][256 c] bf16
//   wkqv  [256 k][768 n]      f32 -> Wkb [768 n][256 k]      bf16
//   wmix  [256 k][256 n]      f32 -> Wmb [256 n][256 k]      bf16
// ---------------------------------------------------------------------------
__global__ __launch_bounds__(256) void prep_tc(const float* __restrict__ image,
                                               const float* __restrict__ wkqv,
                                               const float* __restrict__ wmix,
                                               short* __restrict__ Xb,
                                               short* __restrict__ Wkb,
                                               short* __restrict__ Wmb) {
    __shared__ float tile[64][65];
    const int bid = blockIdx.x;
    const int tid = threadIdx.x;
    const float* src; short* dst;
    int Cc, r0, c0;
    if (bid < 512) {                       // image: 8 nb x (16 t-tiles x 4 c-tiles)
        const int nb = bid >> 6, t = bid & 63;
        src = image + (size_t)nb * C * T;
        dst = Xb + (size_t)nb * T * C;
        Cc = T; r0 = (t & 3) * 64; c0 = (t >> 2) * 64;
    } else if (bid < 560) {                // wkqv: 12 n-tiles x 4 k-tiles
        const int t = bid - 512;
        src = wkqv; dst = Wkb;
        Cc = C3; r0 = (t & 3) * 64; c0 = (t >> 2) * 64;
    } else {                               // wmix: 4 x 4
        const int t = bid - 560;
        src = wmix; dst = Wmb;
        Cc = C; r0 = (t & 3) * 64; c0 = (t >> 2) * 64;
    }
    const int lr = tid >> 4, lc = (tid & 15) * 4;
    #pragma unroll
    for (int p = 0; p < 4; ++p) {
        float4 v = *(const float4*)&src[(size_t)(r0 + 16 * p + lr) * Cc + c0 + lc];
        tile[16 * p + lr][lc + 0] = v.x;
        tile[16 * p + lr][lc + 1] = v.y;
        tile[16 * p + lr][lc + 2] = v.z;
        tile[16 * p + lr][lc + 3] = v.w;
    }
    __syncthreads();
    const int wc = tid >> 2, wr = (tid & 3) * 16;
    bf16x8 v0, v1;
    #pragma unroll
    for (int e = 0; e < 8; ++e) v0[e] = f2bf(tile[wr + e][wc]);
    #pragma unroll
    for (int e = 0; e < 8; ++e) v1[e] = f2bf(tile[wr + 8 + e][wc]);
    short* o = dst + (size_t)(c0 + wc) * C + r0 + wr;    // all dsts have 256 cols
    *(bf16x8*)&o[0] = v0;
    *(bf16x8*)&o[8] = v1;
}

// ---------------------------------------------------------------------------
// Kernel 1: KQV projection — r5 VERBATIM (measured-best). 128x64 tile, BK=64,
// single-buffered global_load_lds, XOR-swizzled LDS, scattered epilogue.
// ---------------------------------------------------------------------------
__global__ __launch_bounds__(256) void kqv_mfma(const short* __restrict__ Xb,
                                                const short* __restrict__ Wkb,
                                                const float* __restrict__ bkqv,
                                                short* __restrict__ Kb,
                                                short* __restrict__ Qb,
                                                short* __restrict__ Vtb) {
    __shared__ __align__(16) short As[128 * 64];   // [t][k], 128B rows, swizzled
    __shared__ __align__(16) short Bs[64 * 64];    // [n][k], 128B rows, swizzled
    const int tid = threadIdx.x;
    const int n0 = blockIdx.x * 64;        // 0..704
    const int m0 = blockIdx.y * 128;
    const int nb = m0 >> 10, t0 = m0 & 1023;
    const int wv = tid >> 6, lane = tid & 63;
    const int m = lane & 15, quad = lane >> 4;

    const short* Xn = Xb + (size_t)nb * T * C + (size_t)t0 * C;
    const short* Wn = Wkb + (size_t)n0 * C;

    f32x4 acc[2][4];
    const f32x4 z = {0.f, 0.f, 0.f, 0.f};
    #pragma unroll
    for (int i = 0; i < 2; ++i)
        #pragma unroll
        for (int j = 0; j < 4; ++j) acc[i][j] = z;

    const int sx = (m & 7) << 4;           // read-side XOR (row&7 == m&7 here)

    for (int k0 = 0; k0 < C; k0 += 64) {
        // stage A (128x64 bf16 = 16KB -> 4 issues/thread), src inverse-swizzled
        #pragma unroll
        for (int p = 0; p < 4; ++p) {
            const int o = p * 4096 + tid * 16;
            const int row = o >> 7;
            const int cb = (o & 127) ^ ((row & 7) << 4);
            gl16(Xn + (size_t)row * C + k0 + (cb >> 1), (char*)As + o);
        }
        // stage B (64x64 bf16 = 8KB -> 2 issues/thread)
        #pragma unroll
        for (int p = 0; p < 2; ++p) {
            const int o = p * 4096 + tid * 16;
            const int row = o >> 7;
            const int cb = (o & 127) ^ ((row & 7) << 4);
            gl16(Wn + (size_t)row * C + k0 + (cb >> 1), (char*)Bs + o);
        }
        __syncthreads();                   // drains vmcnt (compiler-inserted)

        bf16x8 a[2][2], b[2][4];
        #pragma unroll
        for (int kk = 0; kk < 2; ++kk) {
            #pragma unroll
            for (int i = 0; i < 2; ++i)
                a[kk][i] = *(const bf16x8*)((const char*)As +
                            (32 * wv + 16 * i + m) * 128 + ((kk * 64 + quad * 16) ^ sx));
            #pragma unroll
            for (int j = 0; j < 4; ++j)
                b[kk][j] = *(const bf16x8*)((const char*)Bs +
                            (16 * j + m) * 128 + ((kk * 64 + quad * 16) ^ sx));
        }
        #pragma unroll
        for (int kk = 0; kk < 2; ++kk)
            #pragma unroll
            for (int i = 0; i < 2; ++i)
                #pragma unroll
                for (int j = 0; j < 4; ++j)
                    acc[i][j] = mfma32(a[kk][i], b[kk][j], acc[i][j]);
        __syncthreads();                   // frag reads done before next stage
    }

    // epilogue: col jj -> (chunk,h,d); rows = 4 consecutive t per reg set
    #pragma unroll
    for (int j = 0; j < 4; ++j) {
        int jj = n0 + 16 * j + m;
        int chunk = jj >> 8, hh = (jj >> 5) & 7, d = jj & 31;
        float bias = bkqv[jj];
        if (chunk < 2) {
            short* dst = (chunk == 0) ? Kb : Qb;
            float mul = (chunk == 1) ? QSCALE : 1.0f;
            size_t base = (size_t)(nb * NH + hh) * T * HD + d;
            #pragma unroll
            for (int i = 0; i < 2; ++i) {
                int t = t0 + 32 * wv + 16 * i + 4 * quad;
                #pragma unroll
                for (int r = 0; r < 4; ++r)
                    dst[base + (size_t)(t + r) * HD] = f2bf((acc[i][j][r] + bias) * mul);
            }
        } else {
            // V: transposed tile layout [nb][h][tile][d][64]
            size_t base = (size_t)(nb * NH + hh) * (16 * 2048) + (size_t)d * 64;
            #pragma unroll
            for (int i = 0; i < 2; ++i) {
                #pragma unroll
                for (int r = 0; r < 4; ++r) {
                    int t = t0 + 32 * wv + 16 * i + 4 * quad + r;
                    Vtb[base + (size_t)(t >> 6) * 2048 + (t & 63)] = f2bf(acc[i][j][r] + bias);
                }
            }
        }
    }
}

// ---------------------------------------------------------------------------
// Kernel 2: causal flash attention — r5 hybrid VERBATIM (measured-best).
// T_attn ≈ 15.8 µs (r9 replication probe).
// ---------------------------------------------------------------------------
__global__ __launch_bounds__(256) void attn_mfma(const short* __restrict__ Kb,
                                                 const short* __restrict__ Qb,
                                                 const short* __restrict__ Vtb,
                                                 short* __restrict__ attnb) {
    const int qb = (blockIdx.z & 4) ? 7 - blockIdx.x : blockIdx.x;   // 0..7
    const int h  = blockIdx.y;
    const int nb = blockIdx.z;
    const int tid  = threadIdx.x;
    const int wv   = tid >> 6;
    const int lane = tid & 63;
    const int m    = lane & 15;
    const int quad = lane >> 4;

    __shared__ __align__(16) short Ps[128][72];     // probs bf16, wave-private bands

    const int q0  = qb * 128;
    const int nstw = 2 * qb + 1 + (wv >> 1);        // per-wave step count
    const size_t hb = (size_t)(nb * NH + h) * T * HD;
    const short* Kp = Kb + hb;
    const short* Qp = Qb + hb;
    const short* Vp = Vtb + (size_t)(nb * NH + h) * (16 * 2048);
    const f32x4 z = {0.f, 0.f, 0.f, 0.f};

    // Q fragments (B-operand of the swapped S-MFMA): regs for the whole loop
    bf16x8 aq[2];
    #pragma unroll
    for (int i = 0; i < 2; ++i)
        aq[i] = *(const bf16x8*)&Qp[(size_t)(q0 + 32 * wv + 16 * i + m) * HD + 8 * quad];

    // preload K (A-operand) and V (K=32 B-frags) for st = 0
    bf16x8 bk[4], vb[2][2];
    #pragma unroll
    for (int j = 0; j < 4; ++j)
        bk[j] = *(const bf16x8*)&Kp[(size_t)(16 * j + m) * HD + 8 * quad];
    #pragma unroll
    for (int kc = 0; kc < 2; ++kc)
        #pragma unroll
        for (int hf = 0; hf < 2; ++hf)
            vb[kc][hf] = *(const bf16x8*)&Vp[(size_t)(16 * hf + m) * 64 + 32 * kc + 8 * quad];

    f32x4 O[2][2] = {{z, z}, {z, z}};
    float lp[2][2] = {{0.f, 0.f}, {0.f, 0.f}};

    auto step = [&](const int st, const bool msk) {
        // S^T = K Q^T : lane(m,quad) reg r = P[qrow m][k = st*64+16j+4quad+r]
        f32x4 S[2][4];
        #pragma unroll
        for (int i = 0; i < 2; ++i)
            #pragma unroll
            for (int j = 0; j < 4; ++j)
                S[i][j] = mfma32(bk[j], aq[i], z);

        // prefetch next K tile (consumed next iteration)
        if (st + 1 < nstw) {
            #pragma unroll
            for (int j = 0; j < 4; ++j)
                bk[j] = *(const bf16x8*)&Kp[(size_t)((st + 1) * 64 + 16 * j + m) * HD + 8 * quad];
        }

        // softmax: bare exp2 (Q pre-scaled); pack 4 contiguous-k probs -> b64
        const int s0 = st * 64;
        #pragma unroll
        for (int i = 0; i < 2; ++i) {
            const int qr = q0 + 32 * wv + 16 * i + m;
            #pragma unroll
            for (int j = 0; j < 4; ++j) {
                const int kb = s0 + 16 * j + 4 * quad;
                float e0 = __builtin_amdgcn_exp2f(S[i][j][0]);
                float e1 = __builtin_amdgcn_exp2f(S[i][j][1]);
                float e2 = __builtin_amdgcn_exp2f(S[i][j][2]);
                float e3 = __builtin_amdgcn_exp2f(S[i][j][3]);
                if (msk) {
                    if (kb + 0 > qr) e0 = 0.f;
                    if (kb + 1 > qr) e1 = 0.f;
                    if (kb + 2 > qr) e2 = 0.f;
                    if (kb + 3 > qr) e3 = 0.f;
                }
                lp[i][j & 1] += (e0 + e1) + (e2 + e3);   // tree: depth 3, 2 chains
                short4 p4 = { f2bf_trunc(e0), f2bf_trunc(e1),
                              f2bf_trunc(e2), f2bf_trunc(e3) };
                *(short4*)&Ps[32 * wv + 16 * i + m][16 * j + 4 * quad] = p4;
            }
        }

        // O += P V (Ps band is wave-private; lgkmcnt ordering suffices)
        #pragma unroll
        for (int kc = 0; kc < 2; ++kc) {
            bf16x8 ap0 = *(const bf16x8*)&Ps[32 * wv + m][32 * kc + 8 * quad];
            bf16x8 ap1 = *(const bf16x8*)&Ps[32 * wv + 16 + m][32 * kc + 8 * quad];
            O[0][0] = mfma32(ap0, vb[kc][0], O[0][0]);
            O[0][1] = mfma32(ap0, vb[kc][1], O[0][1]);
            O[1][0] = mfma32(ap1, vb[kc][0], O[1][0]);
            O[1][1] = mfma32(ap1, vb[kc][1], O[1][1]);
        }

        // prefetch next V tile (consumed at next iteration's PV)
        if (st + 1 < nstw) {
            const short* Vn = Vp + (size_t)(st + 1) * 2048;
            #pragma unroll
            for (int kc = 0; kc < 2; ++kc)
                #pragma unroll
                for (int hf = 0; hf < 2; ++hf)
                    vb[kc][hf] = *(const bf16x8*)&Vn[(size_t)(16 * hf + m) * 64 + 32 * kc + 8 * quad];
        }
    };

    // bulk (no mask code at all), then 1-2 masked diagonal tiles (per-wave)
    const int mq = 2 * qb;
    for (int st = 0; st < mq; ++st) step(st, false);
    for (int st = mq; st < nstw; ++st) step(st, true);

    // epilogue: lp is lane-local per qrow=m; reduce across quads (2 shuffles),
    // redistribute 1/l to O's row layout (row = 4quad+r) via dynamic shfl.
    #pragma unroll
    for (int i = 0; i < 2; ++i) {
        float l = lp[i][0] + lp[i][1];
        l += __shfl_xor(l, 16);
        l += __shfl_xor(l, 32);            // all quads now hold sum for qrow=m
        #pragma unroll
        for (int r = 0; r < 4; ++r) {
            float lr = __shfl(l, 4 * quad + r);   // lane with m' = 4quad+r
            float inv = 1.f / lr;
            int row = q0 + 32 * wv + 16 * i + 4 * quad + r;
            short* op = attnb + ((size_t)(nb * T + row)) * C + h * HD;
            op[m]      = f2bf(O[i][0][r] * inv);
            op[16 + m] = f2bf(O[i][1][r] * inv);
        }
    }
}

// ---------------------------------------------------------------------------
// Kernel 3: mix projection + residual (r5 verbatim). A-frags load DIRECTLY
// from global; w_mix tile staged from pre-converted bf16 Wmb -> ONE barrier.
// ---------------------------------------------------------------------------
__global__ __launch_bounds__(256) void mix_mfma(const short* __restrict__ attnb,
                                                const short* __restrict__ Wmb,
                                                const float* __restrict__ bmix,
                                                const float* __restrict__ image,
                                                float* __restrict__ out) {
    __shared__ __align__(16) short Bs[64][264];   // [n][k], stride 264 (16B-mult)
    const int tid = threadIdx.x;
    const int n0 = blockIdx.x * 64;        // 0..192
    const int m0 = blockIdx.y * 64;
    const int nb = m0 >> 10, t0 = m0 & 1023;
    const int wv = tid >> 6, lane = tid & 63;
    const int m = lane & 15, quad = lane >> 4;

    // stage entire B tile from bf16: thread -> row n0+(tid>>2), k-quarter (tid&3)
    {
        const short* wrow = Wmb + (size_t)(n0 + (tid >> 2)) * C + (tid & 3) * 64;
        short* brow = &Bs[tid >> 2][(tid & 3) * 64];
        #pragma unroll
        for (int g = 0; g < 8; ++g)
            *(bf16x8*)&brow[8 * g] = *(const bf16x8*)&wrow[8 * g];
    }
    __syncthreads();

    f32x4 acc[4];
    const f32x4 z = {0.f, 0.f, 0.f, 0.f};
    #pragma unroll
    for (int j = 0; j < 4; ++j) acc[j] = z;

    #pragma unroll
    for (int k0 = 0; k0 < C; k0 += 32) {
        bf16x8 a = *(const bf16x8*)&attnb[(size_t)(m0 + 16 * wv + m) * C + k0 + 8 * quad];
        bf16x8 b[4];
        #pragma unroll
        for (int j = 0; j < 4; ++j) b[j] = *(const bf16x8*)&Bs[16 * j + m][k0 + 8 * quad];
        #pragma unroll
        for (int j = 0; j < 4; ++j)
            acc[j] = mfma32(a, b[j], acc[j]);
    }

    // epilogue: out[nb][c][t] = acc + b[c] + image, float4 along t
    const int tb = t0 + 16 * wv + 4 * quad;
    #pragma unroll
    for (int j = 0; j < 4; ++j) {
        int c = n0 + 16 * j + m;
        float bias = bmix[c];
        size_t o = (size_t)(nb * C + c) * T + tb;
        float4 img = *(const float4*)&image[o];
        float4 res = { acc[j][0] + bias + img.x,
                       acc[j][1] + bias + img.y,
                       acc[j][2] + bias + img.z,
                       acc[j][3] + bias + img.w };
        *(float4*)&out[o] = res;
    }
}

// ---------------------------------------------------------------------------
extern "C" void kernel_launch(void* const* d_in, const int* in_sizes, int n_in,
                              void* d_out, int out_size, void* d_ws, size_t ws_size,
                              hipStream_t stream) {
    const float* image = (const float*)d_in[0];
    const float* w_kqv = (const float*)d_in[1];
    const float* b_kqv = (const float*)d_in[2];
    const float* w_mix = (const float*)d_in[3];
    const float* b_mix = (const float*)d_in[4];
    float* out = (float*)d_out;

    short* Xb    = (short*)d_ws;                       // [nb][1024][256] bf16
    short* Wkb   = Xb  + (size_t)NB * T * C;           // [768][256] bf16
    short* Wmb   = Wkb + (size_t)C3 * C;               // [256][256] bf16
    short* Kb    = Wmb + (size_t)C * C;                // [nb*h][1024][32]
    short* Qb    = Kb  + (size_t)NB * NH * T * HD;     // [nb*h][1024][32]
    short* Vtb   = Qb  + (size_t)NB * NH * T * HD;     // [nb*h][16][32][64]
    short* attnb = Vtb + (size_t)NB * NH * T * HD;     // [8192][256]

    // TIMING PROBE 2: prep/kqv/mix x5 (all idempotent), attn x1.
    // S = T_prep+T_kqv+T_mix = (dur - 102.2)/4; overhead = 102.2 - 15.8 - S.
    prep_tc<<<576, 256, 0, stream>>>(image, w_kqv, w_mix, Xb, Wkb, Wmb);
    prep_tc<<<576, 256, 0, stream>>>(image, w_kqv, w_mix, Xb, Wkb, Wmb);
    prep_tc<<<576, 256, 0, stream>>>(image, w_kqv, w_mix, Xb, Wkb, Wmb);
    prep_tc<<<576, 256, 0, stream>>>(image, w_kqv, w_mix, Xb, Wkb, Wmb);
    prep_tc<<<576, 256, 0, stream>>>(image, w_kqv, w_mix, Xb, Wkb, Wmb);
    kqv_mfma<<<dim3(C3 / 64, NB * T / 128), 256, 0, stream>>>(Xb, Wkb, b_kqv, Kb, Qb, Vtb);
    kqv_mfma<<<dim3(C3 / 64, NB * T / 128), 256, 0, stream>>>(Xb, Wkb, b_kqv, Kb, Qb, Vtb);
    kqv_mfma<<<dim3(C3 / 64, NB * T / 128), 256, 0, stream>>>(Xb, Wkb, b_kqv, Kb, Qb, Vtb);
    kqv_mfma<<<dim3(C3 / 64, NB * T / 128), 256, 0, stream>>>(Xb, Wkb, b_kqv, Kb, Qb, Vtb);
    kqv_mfma<<<dim3(C3 / 64, NB * T / 128), 256, 0, stream>>>(Xb, Wkb, b_kqv, Kb, Qb, Vtb);
    attn_mfma<<<dim3(8, NH, NB), 256, 0, stream>>>(Kb, Qb, Vtb, attnb);
    mix_mfma<<<dim3(C / 64, NB * T / 64), 256, 0, stream>>>(attnb, Wmb, b_mix, image, out);
    mix_mfma<<<dim3(C / 64, NB * T / 64), 256, 0, stream>>>(attnb, Wmb, b_mix, image, out);
    mix_mfma<<<dim3(C / 64, NB * T / 64), 256, 0, stream>>>(attnb, Wmb, b_mix, image, out);
    mix_mfma<<<dim3(C / 64, NB * T / 64), 256, 0, stream>>>(attnb, Wmb, b_mix, image, out);
    mix_mfma<<<dim3(C / 64, NB * T / 64), 256, 0, stream>>>(attnb, Wmb, b_mix, image, out);
}

// Round 11
// 102.462 us; speedup vs baseline: 1.7549x; 1.7549x over previous
//
#include <hip/hip_runtime.h>
#include <math.h>

// Problem constants
constexpr int NB  = 8;     // batch
constexpr int C   = 256;   // channels
constexpr int T   = 1024;  // pixels (32*32)
constexpr int NH  = 8;     // heads
constexpr int HD  = 32;    // head dim
constexpr int C3  = 768;   // 3*C

// Q pre-scale: (1/sqrt(32)) * log2(e)  -> softmax body is a bare v_exp_f32
constexpr float QSCALE = 0.25503489422229562f;

typedef __attribute__((ext_vector_type(8))) short bf16x8;
typedef __attribute__((ext_vector_type(4))) float f32x4;

__device__ inline short f2bf(float f) {            // round-to-nearest-even
    unsigned u = __float_as_uint(f);
    u += 0x7FFF + ((u >> 16) & 1);
    return (short)(u >> 16);
}
__device__ inline short f2bf_trunc(float f) {      // 1-op truncation (P only)
    return (short)(__float_as_uint(f) >> 16);
}

__device__ __forceinline__ f32x4 mfma32(bf16x8 a, bf16x8 b, f32x4 c) {
    return __builtin_amdgcn_mfma_f32_16x16x32_bf16(a, b, c, 0, 0, 0);
}

// async global->LDS, 16B per lane. Dest must be wave-uniform base + lane*16.
__device__ __forceinline__ void gl16(const void* g, void* l) {
    __builtin_amdgcn_global_load_lds(
        (const __attribute__((address_space(1))) unsigned int*)g,
        (__attribute__((address_space(3))) unsigned int*)l, 16, 0, 0);
}

// ---------------------------------------------------------------------------
// Kernel 0: one-time transpose+convert to bf16, k-contiguous layouts.
//   image [nb][256 c][1024 t] f32 -> Xb  [nb][1024 t][256 c] bf16
//   wkqv  [256 k][768 n]      f32 -> Wkb [768 n][256 k]      bf16
//   wmix  [256 k][256 n]      f32 -> Wmb [256 n][256 k]      bf16
// ---------------------------------------------------------------------------
__global__ __launch_bounds__(256) void prep_tc(const float* __restrict__ image,
                                               const float* __restrict__ wkqv,
                                               const float* __restrict__ wmix,
                                               short* __restrict__ Xb,
                                               short* __restrict__ Wkb,
                                               short* __restrict__ Wmb) {
    __shared__ float tile[64][65];
    const int bid = blockIdx.x;
    const int tid = threadIdx.x;
    const float* src; short* dst;
    int Cc, r0, c0;
    if (bid < 512) {                       // image: 8 nb x (16 t-tiles x 4 c-tiles)
        const int nb = bid >> 6, t = bid & 63;
        src = image + (size_t)nb * C * T;
        dst = Xb + (size_t)nb * T * C;
        Cc = T; r0 = (t & 3) * 64; c0 = (t >> 2) * 64;
    } else if (bid < 560) {                // wkqv: 12 n-tiles x 4 k-tiles
        const int t = bid - 512;
        src = wkqv; dst = Wkb;
        Cc = C3; r0 = (t & 3) * 64; c0 = (t >> 2) * 64;
    } else {                               // wmix: 4 x 4
        const int t = bid - 560;
        src = wmix; dst = Wmb;
        Cc = C; r0 = (t & 3) * 64; c0 = (t >> 2) * 64;
    }
    const int lr = tid >> 4, lc = (tid & 15) * 4;
    #pragma unroll
    for (int p = 0; p < 4; ++p) {
        float4 v = *(const float4*)&src[(size_t)(r0 + 16 * p + lr) * Cc + c0 + lc];
        tile[16 * p + lr][lc + 0] = v.x;
        tile[16 * p + lr][lc + 1] = v.y;
        tile[16 * p + lr][lc + 2] = v.z;
        tile[16 * p + lr][lc + 3] = v.w;
    }
    __syncthreads();
    const int wc = tid >> 2, wr = (tid & 3) * 16;
    bf16x8 v0, v1;
    #pragma unroll
    for (int e = 0; e < 8; ++e) v0[e] = f2bf(tile[wr + e][wc]);
    #pragma unroll
    for (int e = 0; e < 8; ++e) v1[e] = f2bf(tile[wr + 8 + e][wc]);
    short* o = dst + (size_t)(c0 + wc) * C + r0 + wr;    // all dsts have 256 cols
    *(bf16x8*)&o[0] = v0;
    *(bf16x8*)&o[8] = v1;
}

// ---------------------------------------------------------------------------
// Kernel 1: KQV projection — r5 VERBATIM (measured-best). 128x64 tile, BK=64,
// single-buffered global_load_lds, XOR-swizzled LDS, scattered epilogue.
// ---------------------------------------------------------------------------
__global__ __launch_bounds__(256) void kqv_mfma(const short* __restrict__ Xb,
                                                const short* __restrict__ Wkb,
                                                const float* __restrict__ bkqv,
                                                short* __restrict__ Kb,
                                                short* __restrict__ Qb,
                                                short* __restrict__ Vtb) {
    __shared__ __align__(16) short As[128 * 64];   // [t][k], 128B rows, swizzled
    __shared__ __align__(16) short Bs[64 * 64];    // [n][k], 128B rows, swizzled
    const int tid = threadIdx.x;
    const int n0 = blockIdx.x * 64;        // 0..704
    const int m0 = blockIdx.y * 128;
    const int nb = m0 >> 10, t0 = m0 & 1023;
    const int wv = tid >> 6, lane = tid & 63;
    const int m = lane & 15, quad = lane >> 4;

    const short* Xn = Xb + (size_t)nb * T * C + (size_t)t0 * C;
    const short* Wn = Wkb + (size_t)n0 * C;

    f32x4 acc[2][4];
    const f32x4 z = {0.f, 0.f, 0.f, 0.f};
    #pragma unroll
    for (int i = 0; i < 2; ++i)
        #pragma unroll
        for (int j = 0; j < 4; ++j) acc[i][j] = z;

    const int sx = (m & 7) << 4;           // read-side XOR (row&7 == m&7 here)

    for (int k0 = 0; k0 < C; k0 += 64) {
        // stage A (128x64 bf16 = 16KB -> 4 issues/thread), src inverse-swizzled
        #pragma unroll
        for (int p = 0; p < 4; ++p) {
            const int o = p * 4096 + tid * 16;
            const int row = o >> 7;
            const int cb = (o & 127) ^ ((row & 7) << 4);
            gl16(Xn + (size_t)row * C + k0 + (cb >> 1), (char*)As + o);
        }
        // stage B (64x64 bf16 = 8KB -> 2 issues/thread)
        #pragma unroll
        for (int p = 0; p < 2; ++p) {
            const int o = p * 4096 + tid * 16;
            const int row = o >> 7;
            const int cb = (o & 127) ^ ((row & 7) << 4);
            gl16(Wn + (size_t)row * C + k0 + (cb >> 1), (char*)Bs + o);
        }
        __syncthreads();                   // drains vmcnt (compiler-inserted)

        bf16x8 a[2][2], b[2][4];
        #pragma unroll
        for (int kk = 0; kk < 2; ++kk) {
            #pragma unroll
            for (int i = 0; i < 2; ++i)
                a[kk][i] = *(const bf16x8*)((const char*)As +
                            (32 * wv + 16 * i + m) * 128 + ((kk * 64 + quad * 16) ^ sx));
            #pragma unroll
            for (int j = 0; j < 4; ++j)
                b[kk][j] = *(const bf16x8*)((const char*)Bs +
                            (16 * j + m) * 128 + ((kk * 64 + quad * 16) ^ sx));
        }
        #pragma unroll
        for (int kk = 0; kk < 2; ++kk)
            #pragma unroll
            for (int i = 0; i < 2; ++i)
                #pragma unroll
                for (int j = 0; j < 4; ++j)
                    acc[i][j] = mfma32(a[kk][i], b[kk][j], acc[i][j]);
        __syncthreads();                   // frag reads done before next stage
    }

    // epilogue: col jj -> (chunk,h,d); rows = 4 consecutive t per reg set
    #pragma unroll
    for (int j = 0; j < 4; ++j) {
        int jj = n0 + 16 * j + m;
        int chunk = jj >> 8, hh = (jj >> 5) & 7, d = jj & 31;
        float bias = bkqv[jj];
        if (chunk < 2) {
            short* dst = (chunk == 0) ? Kb : Qb;
            float mul = (chunk == 1) ? QSCALE : 1.0f;
            size_t base = (size_t)(nb * NH + hh) * T * HD + d;
            #pragma unroll
            for (int i = 0; i < 2; ++i) {
                int t = t0 + 32 * wv + 16 * i + 4 * quad;
                #pragma unroll
                for (int r = 0; r < 4; ++r)
                    dst[base + (size_t)(t + r) * HD] = f2bf((acc[i][j][r] + bias) * mul);
            }
        } else {
            // V: transposed tile layout [nb][h][tile][d][64]
            size_t base = (size_t)(nb * NH + hh) * (16 * 2048) + (size_t)d * 64;
            #pragma unroll
            for (int i = 0; i < 2; ++i) {
                #pragma unroll
                for (int r = 0; r < 4; ++r) {
                    int t = t0 + 32 * wv + 16 * i + 4 * quad + r;
                    Vtb[base + (size_t)(t >> 6) * 2048 + (t & 63)] = f2bf(acc[i][j][r] + bias);
                }
            }
        }
    }
}

// ---------------------------------------------------------------------------
// Kernel 2: causal flash attention — r5 hybrid + T5 s_setprio around the
// MFMA clusters. Mechanism (m191): 2 independent blocks/CU run at different
// phases (no inter-block barriers); priority-boosting the MFMA-entering wave
// lets it preempt the other block's exp/pack/load phase. All data paths,
// masks, and accumulation order identical to r5 (bit-exact output).
// ---------------------------------------------------------------------------
__global__ __launch_bounds__(256) void attn_mfma(const short* __restrict__ Kb,
                                                 const short* __restrict__ Qb,
                                                 const short* __restrict__ Vtb,
                                                 short* __restrict__ attnb) {
    const int qb = (blockIdx.z & 4) ? 7 - blockIdx.x : blockIdx.x;   // 0..7
    const int h  = blockIdx.y;
    const int nb = blockIdx.z;
    const int tid  = threadIdx.x;
    const int wv   = tid >> 6;
    const int lane = tid & 63;
    const int m    = lane & 15;
    const int quad = lane >> 4;

    __shared__ __align__(16) short Ps[128][72];     // probs bf16, wave-private bands

    const int q0  = qb * 128;
    const int nstw = 2 * qb + 1 + (wv >> 1);        // per-wave step count
    const size_t hb = (size_t)(nb * NH + h) * T * HD;
    const short* Kp = Kb + hb;
    const short* Qp = Qb + hb;
    const short* Vp = Vtb + (size_t)(nb * NH + h) * (16 * 2048);
    const f32x4 z = {0.f, 0.f, 0.f, 0.f};

    // Q fragments (B-operand of the swapped S-MFMA): regs for the whole loop
    bf16x8 aq[2];
    #pragma unroll
    for (int i = 0; i < 2; ++i)
        aq[i] = *(const bf16x8*)&Qp[(size_t)(q0 + 32 * wv + 16 * i + m) * HD + 8 * quad];

    // preload K (A-operand) and V (K=32 B-frags) for st = 0
    bf16x8 bk[4], vb[2][2];
    #pragma unroll
    for (int j = 0; j < 4; ++j)
        bk[j] = *(const bf16x8*)&Kp[(size_t)(16 * j + m) * HD + 8 * quad];
    #pragma unroll
    for (int kc = 0; kc < 2; ++kc)
        #pragma unroll
        for (int hf = 0; hf < 2; ++hf)
            vb[kc][hf] = *(const bf16x8*)&Vp[(size_t)(16 * hf + m) * 64 + 32 * kc + 8 * quad];

    f32x4 O[2][2] = {{z, z}, {z, z}};
    float lp[2][2] = {{0.f, 0.f}, {0.f, 0.f}};

    auto step = [&](const int st, const bool msk) {
        // S^T = K Q^T : lane(m,quad) reg r = P[qrow m][k = st*64+16j+4quad+r]
        f32x4 S[2][4];
        __builtin_amdgcn_s_setprio(1);     // T5: favor this wave while on matrix pipe
        #pragma unroll
        for (int i = 0; i < 2; ++i)
            #pragma unroll
            for (int j = 0; j < 4; ++j)
                S[i][j] = mfma32(bk[j], aq[i], z);
        __builtin_amdgcn_s_setprio(0);

        // prefetch next K tile (consumed next iteration)
        if (st + 1 < nstw) {
            #pragma unroll
            for (int j = 0; j < 4; ++j)
                bk[j] = *(const bf16x8*)&Kp[(size_t)((st + 1) * 64 + 16 * j + m) * HD + 8 * quad];
        }

        // softmax: bare exp2 (Q pre-scaled); pack 4 contiguous-k probs -> b64
        const int s0 = st * 64;
        #pragma unroll
        for (int i = 0; i < 2; ++i) {
            const int qr = q0 + 32 * wv + 16 * i + m;
            #pragma unroll
            for (int j = 0; j < 4; ++j) {
                const int kb = s0 + 16 * j + 4 * quad;
                float e0 = __builtin_amdgcn_exp2f(S[i][j][0]);
                float e1 = __builtin_amdgcn_exp2f(S[i][j][1]);
                float e2 = __builtin_amdgcn_exp2f(S[i][j][2]);
                float e3 = __builtin_amdgcn_exp2f(S[i][j][3]);
                if (msk) {
                    if (kb + 0 > qr) e0 = 0.f;
                    if (kb + 1 > qr) e1 = 0.f;
                    if (kb + 2 > qr) e2 = 0.f;
                    if (kb + 3 > qr) e3 = 0.f;
                }
                lp[i][j & 1] += (e0 + e1) + (e2 + e3);   // tree: depth 3, 2 chains
                short4 p4 = { f2bf_trunc(e0), f2bf_trunc(e1),
                              f2bf_trunc(e2), f2bf_trunc(e3) };
                *(short4*)&Ps[32 * wv + 16 * i + m][16 * j + 4 * quad] = p4;
            }
        }

        // O += P V (Ps band is wave-private; lgkmcnt ordering suffices)
        __builtin_amdgcn_s_setprio(1);     // T5: PV MFMA cluster
        #pragma unroll
        for (int kc = 0; kc < 2; ++kc) {
            bf16x8 ap0 = *(const bf16x8*)&Ps[32 * wv + m][32 * kc + 8 * quad];
            bf16x8 ap1 = *(const bf16x8*)&Ps[32 * wv + 16 + m][32 * kc + 8 * quad];
            O[0][0] = mfma32(ap0, vb[kc][0], O[0][0]);
            O[0][1] = mfma32(ap0, vb[kc][1], O[0][1]);
            O[1][0] = mfma32(ap1, vb[kc][0], O[1][0]);
            O[1][1] = mfma32(ap1, vb[kc][1], O[1][1]);
        }
        __builtin_amdgcn_s_setprio(0);

        // prefetch next V tile (consumed at next iteration's PV)
        if (st + 1 < nstw) {
            const short* Vn = Vp + (size_t)(st + 1) * 2048;
            #pragma unroll
            for (int kc = 0; kc < 2; ++kc)
                #pragma unroll
                for (int hf = 0; hf < 2; ++hf)
                    vb[kc][hf] = *(const bf16x8*)&Vn[(size_t)(16 * hf + m) * 64 + 32 * kc + 8 * quad];
        }
    };

    // bulk (no mask code at all), then 1-2 masked diagonal tiles (per-wave)
    const int mq = 2 * qb;
    for (int st = 0; st < mq; ++st) step(st, false);
    for (int st = mq; st < nstw; ++st) step(st, true);

    // epilogue: lp is lane-local per qrow=m; reduce across quads (2 shuffles),
    // redistribute 1/l to O's row layout (row = 4quad+r) via dynamic shfl.
    #pragma unroll
    for (int i = 0; i < 2; ++i) {
        float l = lp[i][0] + lp[i][1];
        l += __shfl_xor(l, 16);
        l += __shfl_xor(l, 32);            // all quads now hold sum for qrow=m
        #pragma unroll
        for (int r = 0; r < 4; ++r) {
            float lr = __shfl(l, 4 * quad + r);   // lane with m' = 4quad+r
            float inv = 1.f / lr;
            int row = q0 + 32 * wv + 16 * i + 4 * quad + r;
            short* op = attnb + ((size_t)(nb * T + row)) * C + h * HD;
            op[m]      = f2bf(O[i][0][r] * inv);
            op[16 + m] = f2bf(O[i][1][r] * inv);
        }
    }
}

// ---------------------------------------------------------------------------
// Kernel 3: mix projection + residual (r5 verbatim). A-frags load DIRECTLY
// from global; w_mix tile staged from pre-converted bf16 Wmb -> ONE barrier.
// ---------------------------------------------------------------------------
__global__ __launch_bounds__(256) void mix_mfma(const short* __restrict__ attnb,
                                                const short* __restrict__ Wmb,
                                                const float* __restrict__ bmix,
                                                const float* __restrict__ image,
                                                float* __restrict__ out) {
    __shared__ __align__(16) short Bs[64][264];   // [n][k], stride 264 (16B-mult)
    const int tid = threadIdx.x;
    const int n0 = blockIdx.x * 64;        // 0..192
    const int m0 = blockIdx.y * 64;
    const int nb = m0 >> 10, t0 = m0 & 1023;
    const int wv = tid >> 6, lane = tid & 63;
    const int m = lane & 15, quad = lane >> 4;

    // stage entire B tile from bf16: thread -> row n0+(tid>>2), k-quarter (tid&3)
    {
        const short* wrow = Wmb + (size_t)(n0 + (tid >> 2)) * C + (tid & 3) * 64;
        short* brow = &Bs[tid >> 2][(tid & 3) * 64];
        #pragma unroll
        for (int g = 0; g < 8; ++g)
            *(bf16x8*)&brow[8 * g] = *(const bf16x8*)&wrow[8 * g];
    }
    __syncthreads();

    f32x4 acc[4];
    const f32x4 z = {0.f, 0.f, 0.f, 0.f};
    #pragma unroll
    for (int j = 0; j < 4; ++j) acc[j] = z;

    #pragma unroll
    for (int k0 = 0; k0 < C; k0 += 32) {
        bf16x8 a = *(const bf16x8*)&attnb[(size_t)(m0 + 16 * wv + m) * C + k0 + 8 * quad];
        bf16x8 b[4];
        #pragma unroll
        for (int j = 0; j < 4; ++j) b[j] = *(const bf16x8*)&Bs[16 * j + m][k0 + 8 * quad];
        #pragma unroll
        for (int j = 0; j < 4; ++j)
            acc[j] = mfma32(a, b[j], acc[j]);
    }

    // epilogue: out[nb][c][t] = acc + b[c] + image, float4 along t
    const int tb = t0 + 16 * wv + 4 * quad;
    #pragma unroll
    for (int j = 0; j < 4; ++j) {
        int c = n0 + 16 * j + m;
        float bias = bmix[c];
        size_t o = (size_t)(nb * C + c) * T + tb;
        float4 img = *(const float4*)&image[o];
        float4 res = { acc[j][0] + bias + img.x,
                       acc[j][1] + bias + img.y,
                       acc[j][2] + bias + img.z,
                       acc[j][3] + bias + img.w };
        *(float4*)&out[o] = res;
    }
}

// ---------------------------------------------------------------------------
extern "C" void kernel_launch(void* const* d_in, const int* in_sizes, int n_in,
                              void* d_out, int out_size, void* d_ws, size_t ws_size,
                              hipStream_t stream) {
    const float* image = (const float*)d_in[0];
    const float* w_kqv = (const float*)d_in[1];
    const float* b_kqv = (const float*)d_in[2];
    const float* w_mix = (const float*)d_in[3];
    const float* b_mix = (const float*)d_in[4];
    float* out = (float*)d_out;

    short* Xb    = (short*)d_ws;                       // [nb][1024][256] bf16
    short* Wkb   = Xb  + (size_t)NB * T * C;           // [768][256] bf16
    short* Wmb   = Wkb + (size_t)C3 * C;               // [256][256] bf16
    short* Kb    = Wmb + (size_t)C * C;                // [nb*h][1024][32]
    short* Qb    = Kb  + (size_t)NB * NH * T * HD;     // [nb*h][1024][32]
    short* Vtb   = Qb  + (size_t)NB * NH * T * HD;     // [nb*h][16][32][64]
    short* attnb = Vtb + (size_t)NB * NH * T * HD;     // [8192][256]

    prep_tc<<<576, 256, 0, stream>>>(image, w_kqv, w_mix, Xb, Wkb, Wmb);
    kqv_mfma<<<dim3(C3 / 64, NB * T / 128), 256, 0, stream>>>(Xb, Wkb, b_kqv, Kb, Qb, Vtb);
    attn_mfma<<<dim3(8, NH, NB), 256, 0, stream>>>(Kb, Qb, Vtb, attnb);
    mix_mfma<<<dim3(C / 64, NB * T / 64), 256, 0, stream>>>(attnb, Wmb, b_mix, image, out);
}

// Round 12
// 101.129 us; speedup vs baseline: 1.7780x; 1.0132x over previous
//
#include <hip/hip_runtime.h>
#include <math.h>

// Problem constants
constexpr int NB  = 8;     // batch
constexpr int C   = 256;   // channels
constexpr int T   = 1024;  // pixels (32*32)
constexpr int NH  = 8;     // heads
constexpr int HD  = 32;    // head dim
constexpr int C3  = 768;   // 3*C

// Q pre-scale: (1/sqrt(32)) * log2(e)  -> softmax body is a bare v_exp_f32
constexpr float QSCALE = 0.25503489422229562f;

typedef __attribute__((ext_vector_type(8))) short bf16x8;
typedef __attribute__((ext_vector_type(4))) float f32x4;

__device__ inline short f2bf(float f) {            // round-to-nearest-even
    unsigned u = __float_as_uint(f);
    u += 0x7FFF + ((u >> 16) & 1);
    return (short)(u >> 16);
}
__device__ inline short f2bf_trunc(float f) {      // 1-op truncation (P only)
    return (short)(__float_as_uint(f) >> 16);
}

__device__ __forceinline__ f32x4 mfma32(bf16x8 a, bf16x8 b, f32x4 c) {
    return __builtin_amdgcn_mfma_f32_16x16x32_bf16(a, b, c, 0, 0, 0);
}

// async global->LDS, 16B per lane. Dest must be wave-uniform base + lane*16.
__device__ __forceinline__ void gl16(const void* g, void* l) {
    __builtin_amdgcn_global_load_lds(
        (const __attribute__((address_space(1))) unsigned int*)g,
        (__attribute__((address_space(3))) unsigned int*)l, 16, 0, 0);
}

// ---------------------------------------------------------------------------
// Kernel 0: one-time transpose+convert to bf16, k-contiguous layouts.
//   image [nb][256 c][1024 t] f32 -> Xb  [nb][1024 t][256 c] bf16
//   wkqv  [256 k][768 n]      f32 -> Wkb [768 n][256 k]      bf16
//   wmix  [256 k][256 n]      f32 -> Wmb [256 n][256 k]      bf16
// ---------------------------------------------------------------------------
__global__ __launch_bounds__(256) void prep_tc(const float* __restrict__ image,
                                               const float* __restrict__ wkqv,
                                               const float* __restrict__ wmix,
                                               short* __restrict__ Xb,
                                               short* __restrict__ Wkb,
                                               short* __restrict__ Wmb) {
    __shared__ float tile[64][65];
    const int bid = blockIdx.x;
    const int tid = threadIdx.x;
    const float* src; short* dst;
    int Cc, r0, c0;
    if (bid < 512) {                       // image: 8 nb x (16 t-tiles x 4 c-tiles)
        const int nb = bid >> 6, t = bid & 63;
        src = image + (size_t)nb * C * T;
        dst = Xb + (size_t)nb * T * C;
        Cc = T; r0 = (t & 3) * 64; c0 = (t >> 2) * 64;
    } else if (bid < 560) {                // wkqv: 12 n-tiles x 4 k-tiles
        const int t = bid - 512;
        src = wkqv; dst = Wkb;
        Cc = C3; r0 = (t & 3) * 64; c0 = (t >> 2) * 64;
    } else {                               // wmix: 4 x 4
        const int t = bid - 560;
        src = wmix; dst = Wmb;
        Cc = C; r0 = (t & 3) * 64; c0 = (t >> 2) * 64;
    }
    const int lr = tid >> 4, lc = (tid & 15) * 4;
    #pragma unroll
    for (int p = 0; p < 4; ++p) {
        float4 v = *(const float4*)&src[(size_t)(r0 + 16 * p + lr) * Cc + c0 + lc];
        tile[16 * p + lr][lc + 0] = v.x;
        tile[16 * p + lr][lc + 1] = v.y;
        tile[16 * p + lr][lc + 2] = v.z;
        tile[16 * p + lr][lc + 3] = v.w;
    }
    __syncthreads();
    const int wc = tid >> 2, wr = (tid & 3) * 16;
    bf16x8 v0, v1;
    #pragma unroll
    for (int e = 0; e < 8; ++e) v0[e] = f2bf(tile[wr + e][wc]);
    #pragma unroll
    for (int e = 0; e < 8; ++e) v1[e] = f2bf(tile[wr + 8 + e][wc]);
    short* o = dst + (size_t)(c0 + wc) * C + r0 + wr;    // all dsts have 256 cols
    *(bf16x8*)&o[0] = v0;
    *(bf16x8*)&o[8] = v1;
}

// ---------------------------------------------------------------------------
// Kernel 1: KQV projection — r5 VERBATIM (measured-best). 128x64 tile, BK=64,
// single-buffered global_load_lds, XOR-swizzled LDS, scattered epilogue.
// ---------------------------------------------------------------------------
__global__ __launch_bounds__(256) void kqv_mfma(const short* __restrict__ Xb,
                                                const short* __restrict__ Wkb,
                                                const float* __restrict__ bkqv,
                                                short* __restrict__ Kb,
                                                short* __restrict__ Qb,
                                                short* __restrict__ Vtb) {
    __shared__ __align__(16) short As[128 * 64];   // [t][k], 128B rows, swizzled
    __shared__ __align__(16) short Bs[64 * 64];    // [n][k], 128B rows, swizzled
    const int tid = threadIdx.x;
    const int n0 = blockIdx.x * 64;        // 0..704
    const int m0 = blockIdx.y * 128;
    const int nb = m0 >> 10, t0 = m0 & 1023;
    const int wv = tid >> 6, lane = tid & 63;
    const int m = lane & 15, quad = lane >> 4;

    const short* Xn = Xb + (size_t)nb * T * C + (size_t)t0 * C;
    const short* Wn = Wkb + (size_t)n0 * C;

    f32x4 acc[2][4];
    const f32x4 z = {0.f, 0.f, 0.f, 0.f};
    #pragma unroll
    for (int i = 0; i < 2; ++i)
        #pragma unroll
        for (int j = 0; j < 4; ++j) acc[i][j] = z;

    const int sx = (m & 7) << 4;           // read-side XOR (row&7 == m&7 here)

    for (int k0 = 0; k0 < C; k0 += 64) {
        // stage A (128x64 bf16 = 16KB -> 4 issues/thread), src inverse-swizzled
        #pragma unroll
        for (int p = 0; p < 4; ++p) {
            const int o = p * 4096 + tid * 16;
            const int row = o >> 7;
            const int cb = (o & 127) ^ ((row & 7) << 4);
            gl16(Xn + (size_t)row * C + k0 + (cb >> 1), (char*)As + o);
        }
        // stage B (64x64 bf16 = 8KB -> 2 issues/thread)
        #pragma unroll
        for (int p = 0; p < 2; ++p) {
            const int o = p * 4096 + tid * 16;
            const int row = o >> 7;
            const int cb = (o & 127) ^ ((row & 7) << 4);
            gl16(Wn + (size_t)row * C + k0 + (cb >> 1), (char*)Bs + o);
        }
        __syncthreads();                   // drains vmcnt (compiler-inserted)

        bf16x8 a[2][2], b[2][4];
        #pragma unroll
        for (int kk = 0; kk < 2; ++kk) {
            #pragma unroll
            for (int i = 0; i < 2; ++i)
                a[kk][i] = *(const bf16x8*)((const char*)As +
                            (32 * wv + 16 * i + m) * 128 + ((kk * 64 + quad * 16) ^ sx));
            #pragma unroll
            for (int j = 0; j < 4; ++j)
                b[kk][j] = *(const bf16x8*)((const char*)Bs +
                            (16 * j + m) * 128 + ((kk * 64 + quad * 16) ^ sx));
        }
        #pragma unroll
        for (int kk = 0; kk < 2; ++kk)
            #pragma unroll
            for (int i = 0; i < 2; ++i)
                #pragma unroll
                for (int j = 0; j < 4; ++j)
                    acc[i][j] = mfma32(a[kk][i], b[kk][j], acc[i][j]);
        __syncthreads();                   // frag reads done before next stage
    }

    // epilogue: col jj -> (chunk,h,d); rows = 4 consecutive t per reg set
    #pragma unroll
    for (int j = 0; j < 4; ++j) {
        int jj = n0 + 16 * j + m;
        int chunk = jj >> 8, hh = (jj >> 5) & 7, d = jj & 31;
        float bias = bkqv[jj];
        if (chunk < 2) {
            short* dst = (chunk == 0) ? Kb : Qb;
            float mul = (chunk == 1) ? QSCALE : 1.0f;
            size_t base = (size_t)(nb * NH + hh) * T * HD + d;
            #pragma unroll
            for (int i = 0; i < 2; ++i) {
                int t = t0 + 32 * wv + 16 * i + 4 * quad;
                #pragma unroll
                for (int r = 0; r < 4; ++r)
                    dst[base + (size_t)(t + r) * HD] = f2bf((acc[i][j][r] + bias) * mul);
            }
        } else {
            // V: transposed tile layout [nb][h][tile][d][64]
            size_t base = (size_t)(nb * NH + hh) * (16 * 2048) + (size_t)d * 64;
            #pragma unroll
            for (int i = 0; i < 2; ++i) {
                #pragma unroll
                for (int r = 0; r < 4; ++r) {
                    int t = t0 + 32 * wv + 16 * i + 4 * quad + r;
                    Vtb[base + (size_t)(t >> 6) * 2048 + (t & 63)] = f2bf(acc[i][j][r] + bias);
                }
            }
        }
    }
}

// ---------------------------------------------------------------------------
// Kernel 2: causal flash attention — r5 hybrid + ONE-STEP P PIPELINE.
// Double-buffered Ps; each step: (1) issue ds_reads of P(st-1) from the
// other buffer (no deps), (2) S(st) MFMAs hide the read latency, (3)
// PV(st-1) consumes with no lgkm stall, (4) exp(st)->write own buffer —
// nobody waits on those writes until the NEXT step's reads. The intra-step
// write->drain->read chain (the measured dominant stall) leaves the
// critical path. Accumulation order into O/lp unchanged -> bit-identical.
// ---------------------------------------------------------------------------
__global__ __launch_bounds__(256) void attn_mfma(const short* __restrict__ Kb,
                                                 const short* __restrict__ Qb,
                                                 const short* __restrict__ Vtb,
                                                 short* __restrict__ attnb) {
    const int qb = (blockIdx.z & 4) ? 7 - blockIdx.x : blockIdx.x;   // 0..7
    const int h  = blockIdx.y;
    const int nb = blockIdx.z;
    const int tid  = threadIdx.x;
    const int wv   = tid >> 6;
    const int lane = tid & 63;
    const int m    = lane & 15;
    const int quad = lane >> 4;

    __shared__ __align__(16) short Ps[2][128][72];  // DOUBLE-buffered probs

    const int q0  = qb * 128;
    const int mq  = 2 * qb;
    const int nstw = mq + 1 + (wv >> 1);            // per-wave step count
    const size_t hb = (size_t)(nb * NH + h) * T * HD;
    const short* Kp = Kb + hb;
    const short* Qp = Qb + hb;
    const short* Vp = Vtb + (size_t)(nb * NH + h) * (16 * 2048);
    const f32x4 z = {0.f, 0.f, 0.f, 0.f};

    // Q fragments (B-operand of the swapped S-MFMA): regs for the whole loop
    bf16x8 aq[2];
    #pragma unroll
    for (int i = 0; i < 2; ++i)
        aq[i] = *(const bf16x8*)&Qp[(size_t)(q0 + 32 * wv + 16 * i + m) * HD + 8 * quad];

    // preload K (A-operand) and V (K=32 B-frags) for st = 0
    bf16x8 bk[4], vb[2][2];
    #pragma unroll
    for (int j = 0; j < 4; ++j)
        bk[j] = *(const bf16x8*)&Kp[(size_t)(16 * j + m) * HD + 8 * quad];
    #pragma unroll
    for (int kc = 0; kc < 2; ++kc)
        #pragma unroll
        for (int hf = 0; hf < 2; ++hf)
            vb[kc][hf] = *(const bf16x8*)&Vp[(size_t)(16 * hf + m) * 64 + 32 * kc + 8 * quad];

    f32x4 O[2][2] = {{z, z}, {z, z}};
    float lp[2][2] = {{0.f, 0.f}, {0.f, 0.f}};

    // exp(st) -> lp + pack -> Ps[st&1]  (same math as r5, buffer-indexed)
    auto softmax_store = [&](f32x4 (&S)[2][4], const int st, const bool msk) {
        const int s0 = st * 64;
        const int cb = st & 1;
        #pragma unroll
        for (int i = 0; i < 2; ++i) {
            const int qr = q0 + 32 * wv + 16 * i + m;
            #pragma unroll
            for (int j = 0; j < 4; ++j) {
                const int kb = s0 + 16 * j + 4 * quad;
                float e0 = __builtin_amdgcn_exp2f(S[i][j][0]);
                float e1 = __builtin_amdgcn_exp2f(S[i][j][1]);
                float e2 = __builtin_amdgcn_exp2f(S[i][j][2]);
                float e3 = __builtin_amdgcn_exp2f(S[i][j][3]);
                if (msk) {
                    if (kb + 0 > qr) e0 = 0.f;
                    if (kb + 1 > qr) e1 = 0.f;
                    if (kb + 2 > qr) e2 = 0.f;
                    if (kb + 3 > qr) e3 = 0.f;
                }
                lp[i][j & 1] += (e0 + e1) + (e2 + e3);   // tree: depth 3, 2 chains
                short4 p4 = { f2bf_trunc(e0), f2bf_trunc(e1),
                              f2bf_trunc(e2), f2bf_trunc(e3) };
                *(short4*)&Ps[cb][32 * wv + 16 * i + m][16 * j + 4 * quad] = p4;
            }
        }
    };

    // prologue st = 0: S, exp, store Ps[0] (no PV yet)
    {
        f32x4 S[2][4];
        #pragma unroll
        for (int i = 0; i < 2; ++i)
            #pragma unroll
            for (int j = 0; j < 4; ++j)
                S[i][j] = mfma32(bk[j], aq[i], z);
        if (1 < nstw) {
            #pragma unroll
            for (int j = 0; j < 4; ++j)
                bk[j] = *(const bf16x8*)&Kp[(size_t)(64 + 16 * j + m) * HD + 8 * quad];
        }
        softmax_store(S, 0, mq == 0);
    }

    // pipelined body: reads P(st-1) || S(st) || PV(st-1) || exp/store(st)
    auto body = [&](const int st, const bool msk) {
        const int pb = (st - 1) & 1;
        // (1) issue P(st-1) reads — no dependencies on this step
        bf16x8 ap0[2], ap1[2];
        #pragma unroll
        for (int kc = 0; kc < 2; ++kc) {
            ap0[kc] = *(const bf16x8*)&Ps[pb][32 * wv + m][32 * kc + 8 * quad];
            ap1[kc] = *(const bf16x8*)&Ps[pb][32 * wv + 16 + m][32 * kc + 8 * quad];
        }
        // (2) S(st): 8 independent MFMAs cover the read latency
        f32x4 S[2][4];
        #pragma unroll
        for (int i = 0; i < 2; ++i)
            #pragma unroll
            for (int j = 0; j < 4; ++j)
                S[i][j] = mfma32(bk[j], aq[i], z);
        // (3) PV(st-1): operands landed, no stall; vb = V(st-1)
        #pragma unroll
        for (int kc = 0; kc < 2; ++kc) {
            O[0][0] = mfma32(ap0[kc], vb[kc][0], O[0][0]);
            O[0][1] = mfma32(ap0[kc], vb[kc][1], O[0][1]);
            O[1][0] = mfma32(ap1[kc], vb[kc][0], O[1][0]);
            O[1][1] = mfma32(ap1[kc], vb[kc][1], O[1][1]);
        }
        // (4) prefetch K(st+1)
        if (st + 1 < nstw) {
            #pragma unroll
            for (int j = 0; j < 4; ++j)
                bk[j] = *(const bf16x8*)&Kp[(size_t)((st + 1) * 64 + 16 * j + m) * HD + 8 * quad];
        }
        // (5) exp(st) -> Ps[st&1]; writes drain during next step's phase 1-2
        softmax_store(S, st, msk);
        // (6) vb = V(st) for next step's PV
        const short* Vn = Vp + (size_t)st * 2048;
        #pragma unroll
        for (int kc = 0; kc < 2; ++kc)
            #pragma unroll
            for (int hf = 0; hf < 2; ++hf)
                vb[kc][hf] = *(const bf16x8*)&Vn[(size_t)(16 * hf + m) * 64 + 32 * kc + 8 * quad];
    };

    for (int st = 1; st < mq; ++st) body(st, false);
    for (int st = (mq > 1 ? mq : 1); st < nstw; ++st) body(st, true);

    // tail: PV(nstw-1) from Ps[(nstw-1)&1], vb = V(nstw-1)
    {
        const int pb = (nstw - 1) & 1;
        #pragma unroll
        for (int kc = 0; kc < 2; ++kc) {
            bf16x8 ap0 = *(const bf16x8*)&Ps[pb][32 * wv + m][32 * kc + 8 * quad];
            bf16x8 ap1 = *(const bf16x8*)&Ps[pb][32 * wv + 16 + m][32 * kc + 8 * quad];
            O[0][0] = mfma32(ap0, vb[kc][0], O[0][0]);
            O[0][1] = mfma32(ap0, vb[kc][1], O[0][1]);
            O[1][0] = mfma32(ap1, vb[kc][0], O[1][0]);
            O[1][1] = mfma32(ap1, vb[kc][1], O[1][1]);
        }
    }

    // epilogue: lp is lane-local per qrow=m; reduce across quads (2 shuffles),
    // redistribute 1/l to O's row layout (row = 4quad+r) via dynamic shfl.
    #pragma unroll
    for (int i = 0; i < 2; ++i) {
        float l = lp[i][0] + lp[i][1];
        l += __shfl_xor(l, 16);
        l += __shfl_xor(l, 32);            // all quads now hold sum for qrow=m
        #pragma unroll
        for (int r = 0; r < 4; ++r) {
            float lr = __shfl(l, 4 * quad + r);   // lane with m' = 4quad+r
            float inv = 1.f / lr;
            int row = q0 + 32 * wv + 16 * i + 4 * quad + r;
            short* op = attnb + ((size_t)(nb * T + row)) * C + h * HD;
            op[m]      = f2bf(O[i][0][r] * inv);
            op[16 + m] = f2bf(O[i][1][r] * inv);
        }
    }
}

// ---------------------------------------------------------------------------
// Kernel 3: mix projection + residual (r5 verbatim). A-frags load DIRECTLY
// from global; w_mix tile staged from pre-converted bf16 Wmb -> ONE barrier.
// ---------------------------------------------------------------------------
__global__ __launch_bounds__(256) void mix_mfma(const short* __restrict__ attnb,
                                                const short* __restrict__ Wmb,
                                                const float* __restrict__ bmix,
                                                const float* __restrict__ image,
                                                float* __restrict__ out) {
    __shared__ __align__(16) short Bs[64][264];   // [n][k], stride 264 (16B-mult)
    const int tid = threadIdx.x;
    const int n0 = blockIdx.x * 64;        // 0..192
    const int m0 = blockIdx.y * 64;
    const int nb = m0 >> 10, t0 = m0 & 1023;
    const int wv = tid >> 6, lane = tid & 63;
    const int m = lane & 15, quad = lane >> 4;

    // stage entire B tile from bf16: thread -> row n0+(tid>>2), k-quarter (tid&3)
    {
        const short* wrow = Wmb + (size_t)(n0 + (tid >> 2)) * C + (tid & 3) * 64;
        short* brow = &Bs[tid >> 2][(tid & 3) * 64];
        #pragma unroll
        for (int g = 0; g < 8; ++g)
            *(bf16x8*)&brow[8 * g] = *(const bf16x8*)&wrow[8 * g];
    }
    __syncthreads();

    f32x4 acc[4];
    const f32x4 z = {0.f, 0.f, 0.f, 0.f};
    #pragma unroll
    for (int j = 0; j < 4; ++j) acc[j] = z;

    #pragma unroll
    for (int k0 = 0; k0 < C; k0 += 32) {
        bf16x8 a = *(const bf16x8*)&attnb[(size_t)(m0 + 16 * wv + m) * C + k0 + 8 * quad];
        bf16x8 b[4];
        #pragma unroll
        for (int j = 0; j < 4; ++j) b[j] = *(const bf16x8*)&Bs[16 * j + m][k0 + 8 * quad];
        #pragma unroll
        for (int j = 0; j < 4; ++j)
            acc[j] = mfma32(a, b[j], acc[j]);
    }

    // epilogue: out[nb][c][t] = acc + b[c] + image, float4 along t
    const int tb = t0 + 16 * wv + 4 * quad;
    #pragma unroll
    for (int j = 0; j < 4; ++j) {
        int c = n0 + 16 * j + m;
        float bias = bmix[c];
        size_t o = (size_t)(nb * C + c) * T + tb;
        float4 img = *(const float4*)&image[o];
        float4 res = { acc[j][0] + bias + img.x,
                       acc[j][1] + bias + img.y,
                       acc[j][2] + bias + img.z,
                       acc[j][3] + bias + img.w };
        *(float4*)&out[o] = res;
    }
}

// ---------------------------------------------------------------------------
extern "C" void kernel_launch(void* const* d_in, const int* in_sizes, int n_in,
                              void* d_out, int out_size, void* d_ws, size_t ws_size,
                              hipStream_t stream) {
    const float* image = (const float*)d_in[0];
    const float* w_kqv = (const float*)d_in[1];
    const float* b_kqv = (const float*)d_in[2];
    const float* w_mix = (const float*)d_in[3];
    const float* b_mix = (const float*)d_in[4];
    float* out = (float*)d_out;

    short* Xb    = (short*)d_ws;                       // [nb][1024][256] bf16
    short* Wkb   = Xb  + (size_t)NB * T * C;           // [768][256] bf16
    short* Wmb   = Wkb + (size_t)C3 * C;               // [256][256] bf16
    short* Kb    = Wmb + (size_t)C * C;                // [nb*h][1024][32]
    short* Qb    = Kb  + (size_t)NB * NH * T * HD;     // [nb*h][1024][32]
    short* Vtb   = Qb  + (size_t)NB * NH * T * HD;     // [nb*h][16][32][64]
    short* attnb = Vtb + (size_t)NB * NH * T * HD;     // [8192][256]

    prep_tc<<<576, 256, 0, stream>>>(image, w_kqv, w_mix, Xb, Wkb, Wmb);
    kqv_mfma<<<dim3(C3 / 64, NB * T / 128), 256, 0, stream>>>(Xb, Wkb, b_kqv, Kb, Qb, Vtb);
    attn_mfma<<<dim3(8, NH, NB), 256, 0, stream>>>(Kb, Qb, Vtb, attnb);
    mix_mfma<<<dim3(C / 64, NB * T / 64), 256, 0, stream>>>(attnb, Wmb, b_mix, image, out);
}